// Round 8
// baseline (9477.442 us; speedup 1.0000x reference)
//
#include <hip/hip_runtime.h>

#define KNBR 32
#define NCELL 4096        // 16^3 Morton cells
#define MAXCHUNK 320      // ceil(20000/64)=313 <= 320
#define FCAP (MAXCHUNK * 64)
#define FT 768            // fps threads: 12 waves
#define NWAVE (FT / 64)   // 12
#define NSLOT 27          // chunks per wave: 27*12 = 324 >= 313
#define NP 14             // f32x2 pairs per array (slot 27 = sentinel pad)
#define NG 4              // slot groups: {0-7, 8-15, 16-23, 24-26}

typedef unsigned long long u64;
typedef unsigned int u32;
typedef float f32x2 __attribute__((ext_vector_type(2)));

// Reference-matching squared distance: ((dx*dx + dy*dy) + dz*dz), no FMA contraction.
__device__ __forceinline__ float sq_dist_nofma(float px, float py, float pz,
                                               float cx, float cy, float cz) {
    float dx = __fsub_rn(px, cx);
    float dy = __fsub_rn(py, cy);
    float dz = __fsub_rn(pz, cz);
    return __fadd_rn(__fadd_rn(__fmul_rn(dx, dx), __fmul_rn(dy, dy)), __fmul_rn(dz, dz));
}

__device__ __forceinline__ unsigned spread4(unsigned v) {
    return (v & 1u) | ((v & 2u) << 2) | ((v & 4u) << 4) | ((v & 8u) << 6);
}

// key = md_bits<<24 | (0x7FFF-orig)<<9 | chunk  (init kernel only; fps uses
// the md from bits 24+ as the chunk's initial ub).
__device__ __forceinline__ u64 pack_key(float md, int orig, int c) {
    return (orig != 0x7fffffff)
        ? (((u64)__float_as_uint(md) << 24) | ((u64)(0x7FFFu - (u32)orig) << 9) | (u64)c)
        : 0ull;
}

// Canonical CDNA wave64 u32 max-reduction via DPP; lane 63 holds the max;
// readlane broadcasts. Out-of-pattern lanes contribute 0 (identity for unsigned max).
template<int CTRL, int RM>
__device__ __forceinline__ u32 dppmax_step(u32 v) {
    u32 t = (u32)__builtin_amdgcn_update_dpp(0, (int)v, CTRL, RM, 0xf, false);
    return t > v ? t : v;
}
__device__ __forceinline__ u32 wave_max_u32(u32 v) {
    v = dppmax_step<0x111, 0xf>(v);   // row_shr:1
    v = dppmax_step<0x112, 0xf>(v);   // row_shr:2
    v = dppmax_step<0x114, 0xf>(v);   // row_shr:4
    v = dppmax_step<0x118, 0xf>(v);   // row_shr:8
    v = dppmax_step<0x142, 0xa>(v);   // row_bcast:15 -> rows 1,3
    v = dppmax_step<0x143, 0xc>(v);   // row_bcast:31 -> rows 2,3
    return (u32)__builtin_amdgcn_readlane((int)v, 63);
}
// 16-lane row max (lanes 0-15 of each row identical input -> lane 15 has max)
__device__ __forceinline__ u32 row16_max_u32(u32 v) {
    v = dppmax_step<0x111, 0xf>(v);   // row_shr:1
    v = dppmax_step<0x112, 0xf>(v);   // row_shr:2
    v = dppmax_step<0x114, 0xf>(v);   // row_shr:4
    v = dppmax_step<0x118, 0xf>(v);   // row_shr:8
    return (u32)__builtin_amdgcn_readlane((int)v, 15);
}

// branchless 5-way take
__device__ __forceinline__ void take5(bool t, u32& bh, u32& bl, float& bx, float& by, float& bz,
                                      u32 nh, u32 nl, float nx, float ny, float nz) {
    bh = t ? nh : bh; bl = t ? nl : bl;
    bx = t ? nx : bx; by = t ? ny : by; bz = t ? nz : bz;
}

__device__ __forceinline__ float readlane_f(float v, int l) {
    return __uint_as_float((u32)__builtin_amdgcn_readlane(__float_as_int(v), l));
}

// K1: AoS -> SoA + norms + Morton cell id + within-cell rank (counting-sort pass 1)
__global__ void prep_kernel(const float* __restrict__ coord, int N,
                            float* __restrict__ sx, float* __restrict__ sy,
                            float* __restrict__ sz, float* __restrict__ sn,
                            int* __restrict__ cell, int* __restrict__ rank,
                            int* __restrict__ hist) {
    int i = blockIdx.x * blockDim.x + threadIdx.x;
    if (i < N) {
        float x = coord[3 * i + 0];
        float y = coord[3 * i + 1];
        float z = coord[3 * i + 2];
        sx[i] = x; sy[i] = y; sz[i] = z;
        sn[i] = __fadd_rn(__fadd_rn(__fmul_rn(x, x), __fmul_rn(y, y)), __fmul_rn(z, z));
        int ix = (int)(x * 16.0f); ix = ix < 0 ? 0 : (ix > 15 ? 15 : ix);
        int iy = (int)(y * 16.0f); iy = iy < 0 ? 0 : (iy > 15 ? 15 : iy);
        int iz = (int)(z * 16.0f); iz = iz < 0 ? 0 : (iz > 15 ? 15 : iz);
        unsigned mc = spread4(ix) | (spread4(iy) << 1) | (spread4(iz) << 2);
        cell[i] = (int)mc;
        rank[i] = atomicAdd(&hist[mc], 1);
    }
}

// K2: exclusive scan of 4096-bin histogram
__global__ __launch_bounds__(1024) void scan_kernel(const int* __restrict__ hist,
                                                    int* __restrict__ cellstart) {
    __shared__ int buf[1024];
    int t = threadIdx.x;
    int h0 = hist[4 * t], h1 = hist[4 * t + 1], h2 = hist[4 * t + 2], h3 = hist[4 * t + 3];
    int s = h0 + h1 + h2 + h3;
    buf[t] = s;
    __syncthreads();
    for (int off = 1; off < 1024; off <<= 1) {
        int v = (t >= off) ? buf[t - off] : 0;
        __syncthreads();
        buf[t] += v;
        __syncthreads();
    }
    int ex = buf[t] - s;
    cellstart[4 * t]     = ex;
    cellstart[4 * t + 1] = ex + h0;
    cellstart[4 * t + 2] = ex + h0 + h1;
    cellstart[4 * t + 3] = ex + h0 + h1 + h2;
}

// K3: scatter into Morton order, packed as (x, y, z, orig_idx_bits)
__global__ void scatter_kernel(const float* __restrict__ sx, const float* __restrict__ sy,
                               const float* __restrict__ sz,
                               const int* __restrict__ cell, const int* __restrict__ rank,
                               const int* __restrict__ cellstart, int N,
                               float4* __restrict__ pts) {
    int i = blockIdx.x * blockDim.x + threadIdx.x;
    if (i < N) {
        int pos = cellstart[cell[i]] + rank[i];
        pts[pos] = make_float4(sx[i], sy[i], sz[i], __int_as_float(i));
    }
}

// K3b: sentinel padding
__global__ void pad_kernel(float4* __restrict__ pts, int N, int cap) {
    int i = N + blockIdx.x * blockDim.x + threadIdx.x;
    if (i < cap) pts[i] = make_float4(1e18f, 1e18f, 1e18f, __int_as_float(0x7fffffff));
}

// K3c: per-chunk init — md vs original point 0, chunk sphere, chunk key (-> ub).
__global__ void init_chunk_kernel(const float4* __restrict__ pts,
                                  const float* __restrict__ coord,
                                  float* __restrict__ mdbuf,
                                  float4* __restrict__ spheres,
                                  u64* __restrict__ ckeys,
                                  float4* __restrict__ wxyz_g) {
    int c = blockIdx.x, lane = threadIdx.x;
    int pos = (c << 6) + lane;
    float4 P = pts[pos];
    int orig = __float_as_int(P.w);
    bool real = (orig != 0x7fffffff);
    float c0x = coord[0], c0y = coord[1], c0z = coord[2];
    float d = sq_dist_nofma(P.x, P.y, P.z, c0x, c0y, c0z);
    float m = real ? d : -3e38f;
    mdbuf[pos] = m;
    u64 kself = pack_key(m, orig, c);
    u64 key = kself;
    float mnx = real ? P.x : 1e30f, mxx = real ? P.x : -1e30f;
    float mny = real ? P.y : 1e30f, mxy = real ? P.y : -1e30f;
    float mnz = real ? P.z : 1e30f, mxz = real ? P.z : -1e30f;
    #pragma unroll
    for (int off = 32; off; off >>= 1) {
        u64 k2 = __shfl_xor(key, off, 64);
        if (k2 > key) key = k2;
        mnx = fminf(mnx, __shfl_xor(mnx, off, 64));
        mxx = fmaxf(mxx, __shfl_xor(mxx, off, 64));
        mny = fminf(mny, __shfl_xor(mny, off, 64));
        mxy = fmaxf(mxy, __shfl_xor(mxy, off, 64));
        mnz = fminf(mnz, __shfl_xor(mnz, off, 64));
        mxz = fmaxf(mxz, __shfl_xor(mxz, off, 64));
    }
    if (kself == key) wxyz_g[c] = make_float4(P.x, P.y, P.z, 0.f);  // unique owner lane
    if (lane == 0) {
        float cx = 0.5f * (mnx + mxx), cy = 0.5f * (mny + mxy), cz = 0.5f * (mnz + mxz);
        float ex = (mxx - mnx) * 0.5f, ey = (mxy - mny) * 0.5f, ez = (mxz - mnz) * 0.5f;
        float r = sqrtf(ex * ex + ey * ey + ez * ez) * 1.0001f + 1e-7f;
        spheres[c] = make_float4(cx, cy, cz, r);
        ckeys[c] = key;
    }
}

// K4: chunked FPS, round-20: R7 frame + FOLD-BASED selection (no per-chunk
// reduces at all) + ub-prune.
// Selection: per-lane per-group argmax caches (key = md_bits : s15, s15 =
// 0x7FFF-orig so max => max md then min orig — R3/R4-validated encoding);
// refold ONLY groups whose change-ballots fired since their last fold; merge
// NG + ONE 2-phase DPP wave max; waves with no changes skip everything and
// lane 0 re-posts the cached winner. Prune: per-chunk STALE upper bound ub
// (>= chunk max md; mds only decrease) with ballot-gated halving (two levels,
// /2 and /4, ~8 VALU per active chunk, no reduce): (D-rad)^2 > ub-threshold
// proves no point in the chunk changes -> exact. Winner's chunk: D <= rad <=
// thr so never pruned. Dist pass: R7's packed f32x2 pairs, contract(off).
__global__ __launch_bounds__(FT, 3)
void fps_kernel(const float4* __restrict__ pts,
                const float* __restrict__ coord,
                const float4* __restrict__ spheres_g, const u64* __restrict__ ckeys_g,
                int nchunk, int n_dst, int* __restrict__ out_idx) {
#pragma clang fp contract(off)
    __shared__ u64    wwin[2][16];          // padded: [12..15] stay 0 forever
    __shared__ float4 wcoord[2][NWAVE];

    const int tid = threadIdx.x, lane = tid & 63, wv = tid / 64;
    const int myc = lane * NWAVE + wv;     // lane r of wave wv owns chunk r*NWAVE+wv

    const float c0x = coord[0], c0y = coord[1], c0z = coord[2];

    // ---- register-resident point state (f32x2 pairs; slot 27 = sentinel) ----
    f32x2 px2[NP], py2[NP], pz2[NP], md2[NP];
    u32   po[NP];                          // two 16-bit s15 fields (0x7FFF-orig); 0 = sentinel
    #pragma unroll
    for (int i = 0; i < NP; ++i) {
        px2[i] = (f32x2)(0.f); py2[i] = (f32x2)(0.f);
        pz2[i] = (f32x2)(0.f); md2[i] = (f32x2)(0.f);
        po[i] = 0u;
    }
    #pragma unroll
    for (int r = 0; r < NSLOT; ++r) {
        int c = r * NWAVE + wv;
        float x = 0.f, y = 0.f, z = 0.f, md = 0.f;
        u32 ss = 0u;
        if (c < nchunk) {                           // wave-uniform
            float4 P = pts[(c << 6) + lane];
            int orig = __float_as_int(P.w);
            x = P.x; y = P.y; z = P.z;
            if (orig != 0x7fffffff) {
                ss = 0x7FFFu - (u32)orig;
                // bit-identical to init_chunk's md -> ub stays an upper bound
                md = sq_dist_nofma(x, y, z, c0x, c0y, c0z);
            }
        }
        const int i = r >> 1;
        if (r & 1) { px2[i].y = x; py2[i].y = y; pz2[i].y = z; md2[i].y = md;
                     po[i] |= (ss << 16); }
        else       { px2[i].x = x; py2[i].x = y; pz2[i].x = z; md2[i].x = md;
                     po[i] |= ss; }
    }

    // ---- per-owned-chunk prune state (lane r owns chunk r*NWAVE+wv) ----
    bool  has = (lane < NSLOT) && (myc < nchunk);
    float ub = 0.f;                         // stale upper bound on chunk max md
    float4 S = make_float4(1e18f, 1e18f, 1e18f, 0.f);   // own chunk's sphere
    if (has) {
        ub = __uint_as_float((u32)(ckeys_g[myc] >> 24));
        S = spheres_g[myc];
    }

    // per-lane per-group cached argmax (key hi, key lo, winner coords)
    u32 gh[NG], gl[NG]; float gx[NG], gy[NG], gz[NG];
    u64 accg[NG];
    #pragma unroll
    for (int g = 0; g < NG; ++g) { gh[g] = 0; gl[g] = 0; gx[g] = gy[g] = gz[g] = 0.f;
                                   accg[g] = ~0ull; }   // force full fold at s=1
    // cached wave winner (wave-uniform after each recompute)
    u64 ck = 0ull; float cwx = 0.f, cwy = 0.f, cwz = 0.f;

    if (tid == 0) out_idx[0] = 0;
    if (tid < 16) { wwin[0][tid] = 0ull; wwin[1][tid] = 0ull; }   // pad zeros
    __syncthreads();

    int par = 1;
    for (int s = 1; s < n_dst; ++s) {
        // (A) refold changed groups + recompute wave winner; skip all if clean.
        u64 af = accg[0] | accg[1] | accg[2] | accg[3];
        if (af) {
            #pragma unroll
            for (int g = 0; g < NG; ++g) {
                if (accg[g]) {
                    accg[g] = 0ull;
                    const int r0 = g * 8;
                    const int r1 = (g == NG - 1) ? NSLOT : (r0 + 8);
                    u32 bh = 0, bl = 0; float bx = 0.f, by = 0.f, bz = 0.f;
                    #pragma unroll
                    for (int r = r0; r < r1; ++r) {
                        const int i = r >> 1, h = r & 1;
                        u32 nh  = __float_as_uint(h ? md2[i].y : md2[i].x);
                        u32 nl  = (po[i] >> (16 * h)) & 0xFFFFu;
                        float nx = h ? px2[i].y : px2[i].x;
                        float ny = h ? py2[i].y : py2[i].x;
                        float nz = h ? pz2[i].y : pz2[i].x;
                        bool t = (nh > bh) || (nh == bh && nl > bl);
                        take5(t, bh, bl, bx, by, bz, nh, nl, nx, ny, nz);
                    }
                    gh[g] = bh; gl[g] = bl; gx[g] = bx; gy[g] = by; gz[g] = bz;
                }
            }
            // merge NG groups -> per-lane candidate
            u32 whi = gh[0], wlo = gl[0]; float wx = gx[0], wy = gy[0], wz = gz[0];
            #pragma unroll
            for (int g = 1; g < NG; ++g) {
                bool t = (gh[g] > whi) || (gh[g] == whi && gl[g] > wlo);
                take5(t, whi, wlo, wx, wy, wz, gh[g], gl[g], gx[g], gy[g], gz[g]);
            }
            // ONE 2-phase DPP wave max (unique-winner shortcut on lo word)
            u32 mhi = wave_max_u32(whi);
            u64 tbA = __ballot(whi == mhi);
            u32 mlo; int wl;
            if (__popcll(tbA) == 1) {
                wl = (int)(__ffsll((long long)tbA) - 1);
                mlo = (u32)__builtin_amdgcn_readlane((int)wlo, wl);
            } else {
                mlo = wave_max_u32(whi == mhi ? wlo : 0u);
                wl = (int)(__ffsll((long long)__ballot(whi == mhi && wlo == mlo)) - 1);
            }
            ck = ((u64)mhi << 32) | mlo;
            cwx = readlane_f(wx, wl); cwy = readlane_f(wy, wl); cwz = readlane_f(wz, wl);
        }
        if (lane == 0) {
            wwin[par][wv]   = ck;
            wcoord[par][wv] = make_float4(cwx, cwy, cwz, 0.f);
        }
        // prune threshold from (possibly stale) ub: conservative, pre-barrier
        float thr = -1.0f;
        if (has) {
            float t0 = sqrtf(ub) * 1.0001f + S.w;
            thr = t0 * t0 * 1.0002f + 1e-12f;
        }
        __syncthreads();                    // the ONLY barrier per step

        // (B) cross-wave scan via DPP row16 max (lanes 0-15 mirror across rows)
        u64 wval = wwin[par][lane & 15];
        u32 shi = (u32)(wval >> 32), slo = (u32)wval;
        u32 mhiS = row16_max_u32(shi);
        u64 tbS = __ballot((lane < 16) && shi == mhiS);
        u32 mloS; int wb;
        if (__popcll(tbS) == 1) {
            wb = (int)(__ffsll((long long)tbS) - 1);
            mloS = (u32)__builtin_amdgcn_readlane((int)slo, wb);
        } else {
            mloS = row16_max_u32((shi == mhiS && lane < 16) ? slo : 0u);
            wb = (int)(__ffsll((long long)__ballot((lane < 16) && shi == mhiS
                                                   && slo == mloS)) - 1);
        }
        u64 kb = ((u64)mhiS << 32) | mloS;
        float4 C4 = wcoord[par][wb];
        float ncx = C4.x, ncy = C4.y, ncz = C4.z;
        if (tid == 0) out_idx[s] = (int)(0x7FFFu - (u32)(kb & 0x7FFFull));
        par ^= 1;

        // (C) prune own chunk. Winner's chunk never pruned (D <= rad -> D2 <= thr).
        bool act = false;
        if (has) {
            float Dx = ncx - S.x, Dy = ncy - S.y, Dz = ncz - S.z;
            float D2 = Dx * Dx + Dy * Dy + Dz * Dz;
            act = (D2 <= thr);
        }
        u64 m = __ballot(act);              // bit r -> chunk r*NWAVE+wv active

        // (D) packed pair dist pass over active pairs; accumulate change
        // ballots; ballot-gated ub halving (2 levels) per active slot.
        f32x2 nx2; nx2.x = ncx; nx2.y = ncx;
        f32x2 ny2; ny2.x = ncy; ny2.y = ncy;
        f32x2 nz2; nz2.x = ncz; nz2.y = ncz;
        #pragma unroll
        for (int i = 0; i < NP; ++i) {
            if ((m >> (2 * i)) & 3ull) {    // either slot of the pair active
                f32x2 dx = px2[i] - nx2;
                f32x2 dy = py2[i] - ny2;
                f32x2 dz = pz2[i] - nz2;
                f32x2 dd = (dx * dx + dy * dy) + dz * dz;   // contract(off)
                bool ca = dd.x < md2[i].x;  // pruned/sentinel slots: never true
                bool cb = dd.y < md2[i].y;
                u64 mca = __ballot(ca);
                u64 mcb = __ballot(cb);
                accg[i >> 2] |= mca | mcb;
                md2[i].x = ca ? dd.x : md2[i].x;
                md2[i].y = cb ? dd.y : md2[i].y;
                // ub decay: chunk r's mds all < ub/2 (/4) -> halve (quarter)
                #pragma unroll
                for (int h = 0; h < 2; ++h) {
                    const int r = 2 * i + h;
                    if ((m >> r) & 1ull) {
                        float ubb = readlane_f(ub, r);
                        float mdv = h ? md2[i].y : md2[i].x;
                        u64 b2 = __ballot(mdv >= 0.50f * ubb);
                        u64 b4 = __ballot(mdv >= 0.25f * ubb);
                        if (lane == r) {
                            if (!b4)      ub *= 0.25f;
                            else if (!b2) ub *= 0.50f;
                        }
                    }
                }
            }
        }
    }
}

// K5: ball query, one wave per dst. First K in-radius src indices in ascending order.
__global__ void ball_kernel(const float* __restrict__ sx, const float* __restrict__ sy,
                            const float* __restrict__ sz, const float* __restrict__ sn,
                            const int* __restrict__ idx,
                            const float* __restrict__ coord, const int* __restrict__ batch,
                            int N, int n_dst,
                            float* __restrict__ out_coord, float* __restrict__ out_esrc,
                            float* __restrict__ out_edst, float* __restrict__ out_deg,
                            float* __restrict__ out_batch,
                            int* __restrict__ nbr_i, int* __restrict__ deg_i) {
    const int d    = blockIdx.x;
    const int lane = threadIdx.x;   // block of 64
    __shared__ int nbr[KNBR];

    const int id = idx[d];
    const float cx = sx[id], cy = sy[id], cz = sz[id];
    const float dn = sn[id];
    const float RR = (float)(0.08 * 0.08);

    int cnt = 0;
    for (int base = 0; base < N && cnt < KNBR; base += 64) {
        int i = base + lane;
        bool in = false;
        if (i < N) {
            float t     = __fmul_rn(sx[i], cx);
            float inner = __fmaf_rn(sy[i], cy, t);
            inner       = __fmaf_rn(sz[i], cz, inner);
            float d2    = __fsub_rn(__fadd_rn(dn, sn[i]), __fmul_rn(2.0f, inner));
            in = (d2 <= RR);
        }
        unsigned long long m = __ballot(in);
        int pos = cnt + __popcll(m & ((1ull << lane) - 1ull));
        if (in && pos < KNBR) nbr[pos] = i;
        cnt += (int)__popcll(m);
    }
    __syncthreads();

    int deg = cnt < KNBR ? cnt : KNBR;
    if (lane < KNBR) {
        int e = (lane < deg) ? nbr[lane] : -1;
        out_esrc[d * KNBR + lane] = (float)e;
        out_edst[d * KNBR + lane] = (float)((lane < deg) ? d : -1);
        nbr_i[d * KNBR + lane] = e;
    }
    if (lane == 0) { out_deg[d] = (float)deg; deg_i[d] = deg; }
    if (lane < 3)  out_coord[d * 3 + lane] = coord[id * 3 + lane];
    if (lane == 3) out_batch[d] = (float)batch[id];
}

// K6: scatter-mean of gathered features. One block per dst, one thread per feature dim.
__global__ void agg_kernel(const float* __restrict__ feat,
                           const int* __restrict__ nbr_i, const int* __restrict__ deg_i,
                           int F, float* __restrict__ out_feat) {
    const int d = blockIdx.x;
    const int t = threadIdx.x;  // F threads
    const int deg = deg_i[d];
    float acc = 0.0f;
    for (int k = 0; k < deg; ++k) {
        int nb = nbr_i[d * KNBR + k];
        acc = __fadd_rn(acc, feat[nb * F + t]);
    }
    float den = (float)(deg > 0 ? deg : 1);
    out_feat[d * F + t] = acc / den;
}

extern "C" void kernel_launch(void* const* d_in, const int* in_sizes, int n_in,
                              void* d_out, int out_size, void* d_ws, size_t ws_size,
                              hipStream_t stream) {
    const float* coord = (const float*)d_in[0];
    const float* feat  = (const float*)d_in[1];
    const int*   batch = (const int*)d_in[2];

    const int N      = in_sizes[0] / 3;
    const int F      = in_sizes[1] / N;
    const int n_dst  = N / 4;                 // RATIO = 0.25
    const int nchunk = (N + 63) / 64;         // 313

    // workspace layout (pts 16B-aligned: 4N floats precede it; N=20000 -> 320000 B)
    float*  sx      = (float*)d_ws;
    float*  sy      = sx + N;
    float*  sz      = sy + N;
    float*  sn      = sz + N;
    float4* pts     = (float4*)(sn + N);      // FCAP packed points
    float4* spheres = pts + FCAP;             // MAXCHUNK
    float4* wxyz_g  = spheres + MAXCHUNK;     // MAXCHUNK winner coords
    float*  mdbuf   = (float*)(wxyz_g + MAXCHUNK);    // FCAP floats
    u64*    ckeys   = (u64*)(mdbuf + FCAP);   // MAXCHUNK (8B-aligned)
    int*    cell      = (int*)(ckeys + MAXCHUNK);
    int*    rank      = cell + N;
    int*    hist      = rank + N;
    int*    cellstart = hist + NCELL;
    int*    idx       = cellstart + NCELL;
    int*    nbr_i     = idx + n_dst;
    int*    deg_i     = nbr_i + n_dst * KNBR;

    // output layout (all float32), reference return order
    float* out     = (float*)d_out;
    float* o_coord = out;                         // n_dst*3
    float* o_feat  = o_coord + (size_t)n_dst * 3; // n_dst*F
    float* o_esrc  = o_feat  + (size_t)n_dst * F; // n_dst*K
    float* o_edst  = o_esrc  + (size_t)n_dst * KNBR;
    float* o_deg   = o_edst  + (size_t)n_dst * KNBR;
    float* o_batch = o_deg   + n_dst;

    hipMemsetAsync(hist, 0, NCELL * sizeof(int), stream);
    prep_kernel<<<(N + 255) / 256, 256, 0, stream>>>(coord, N, sx, sy, sz, sn,
                                                     cell, rank, hist);
    scan_kernel<<<1, 1024, 0, stream>>>(hist, cellstart);
    scatter_kernel<<<(N + 255) / 256, 256, 0, stream>>>(sx, sy, sz, cell, rank,
                                                        cellstart, N, pts);
    pad_kernel<<<(nchunk * 64 - N + 255) / 256, 256, 0, stream>>>(pts, N, nchunk * 64);
    init_chunk_kernel<<<nchunk, 64, 0, stream>>>(pts, coord, mdbuf, spheres, ckeys,
                                                 wxyz_g);
    fps_kernel<<<1, FT, 0, stream>>>(pts, coord, spheres, ckeys,
                                     nchunk, n_dst, idx);
    ball_kernel<<<n_dst, 64, 0, stream>>>(sx, sy, sz, sn, idx, coord, batch, N, n_dst,
                                          o_coord, o_esrc, o_edst, o_deg, o_batch,
                                          nbr_i, deg_i);
    agg_kernel<<<n_dst, F, 0, stream>>>(feat, nbr_i, deg_i, F, o_feat);
}

// Round 9
// 7725.489 us; speedup vs baseline: 1.2268x; 1.2268x over previous
//
#include <hip/hip_runtime.h>

#define KNBR 32
#define NCELL 4096        // 16^3 Morton cells
#define MAXCHUNK 320      // ceil(20000/64)=313 <= 320
#define FCAP (MAXCHUNK * 64)
#define FT 768            // fps threads: 12 waves
#define NWAVE (FT / 64)   // 12
#define NSLOT 27          // chunks per wave: 27*12 = 324 >= 313
#define NP 14             // f32x2 pairs per array (slot 27 = sentinel pad)

typedef unsigned long long u64;
typedef unsigned int u32;
typedef float f32x2 __attribute__((ext_vector_type(2)));

// Reference-matching squared distance: ((dx*dx + dy*dy) + dz*dz), no FMA contraction.
__device__ __forceinline__ float sq_dist_nofma(float px, float py, float pz,
                                               float cx, float cy, float cz) {
    float dx = __fsub_rn(px, cx);
    float dy = __fsub_rn(py, cy);
    float dz = __fsub_rn(pz, cz);
    return __fadd_rn(__fadd_rn(__fmul_rn(dx, dx), __fmul_rn(dy, dy)), __fmul_rn(dz, dz));
}

__device__ __forceinline__ unsigned spread4(unsigned v) {
    return (v & 1u) | ((v & 2u) << 2) | ((v & 4u) << 4) | ((v & 8u) << 6);
}

// key = md_bits<<24 | (0x7FFF-orig)<<9 | chunk  (orig<32768, chunk<512).
// u64 max == (max md, then min orig); chunk id rides along. Sentinels -> key 0.
__device__ __forceinline__ u64 pack_key(float md, int orig, int c) {
    return (orig != 0x7fffffff)
        ? (((u64)__float_as_uint(md) << 24) | ((u64)(0x7FFFu - (u32)orig) << 9) | (u64)c)
        : 0ull;
}

// Canonical CDNA wave64 u32 max-reduction via DPP; lane 63 holds the max;
// readlane broadcasts. Out-of-pattern lanes contribute 0 (identity for unsigned max).
template<int CTRL, int RM>
__device__ __forceinline__ u32 dppmax_step(u32 v) {
    u32 t = (u32)__builtin_amdgcn_update_dpp(0, (int)v, CTRL, RM, 0xf, false);
    return t > v ? t : v;
}
__device__ __forceinline__ u32 wave_max_u32(u32 v) {
    v = dppmax_step<0x111, 0xf>(v);   // row_shr:1
    v = dppmax_step<0x112, 0xf>(v);   // row_shr:2
    v = dppmax_step<0x114, 0xf>(v);   // row_shr:4
    v = dppmax_step<0x118, 0xf>(v);   // row_shr:8
    v = dppmax_step<0x142, 0xa>(v);   // row_bcast:15 -> rows 1,3
    v = dppmax_step<0x143, 0xc>(v);   // row_bcast:31 -> rows 2,3
    return (u32)__builtin_amdgcn_readlane((int)v, 63);
}
// 16-lane row max (lanes 0-15 of each row identical input -> lane 15 has max)
__device__ __forceinline__ u32 row16_max_u32(u32 v) {
    v = dppmax_step<0x111, 0xf>(v);   // row_shr:1
    v = dppmax_step<0x112, 0xf>(v);   // row_shr:2
    v = dppmax_step<0x114, 0xf>(v);   // row_shr:4
    v = dppmax_step<0x118, 0xf>(v);   // row_shr:8
    return (u32)__builtin_amdgcn_readlane((int)v, 15);
}

__device__ __forceinline__ float readlane_f(float v, int l) {
    return __uint_as_float((u32)__builtin_amdgcn_readlane(__float_as_int(v), l));
}

// K1: AoS -> SoA + norms + Morton cell id + within-cell rank (counting-sort pass 1)
__global__ void prep_kernel(const float* __restrict__ coord, int N,
                            float* __restrict__ sx, float* __restrict__ sy,
                            float* __restrict__ sz, float* __restrict__ sn,
                            int* __restrict__ cell, int* __restrict__ rank,
                            int* __restrict__ hist) {
    int i = blockIdx.x * blockDim.x + threadIdx.x;
    if (i < N) {
        float x = coord[3 * i + 0];
        float y = coord[3 * i + 1];
        float z = coord[3 * i + 2];
        sx[i] = x; sy[i] = y; sz[i] = z;
        sn[i] = __fadd_rn(__fadd_rn(__fmul_rn(x, x), __fmul_rn(y, y)), __fmul_rn(z, z));
        int ix = (int)(x * 16.0f); ix = ix < 0 ? 0 : (ix > 15 ? 15 : ix);
        int iy = (int)(y * 16.0f); iy = iy < 0 ? 0 : (iy > 15 ? 15 : iy);
        int iz = (int)(z * 16.0f); iz = iz < 0 ? 0 : (iz > 15 ? 15 : iz);
        unsigned mc = spread4(ix) | (spread4(iy) << 1) | (spread4(iz) << 2);
        cell[i] = (int)mc;
        rank[i] = atomicAdd(&hist[mc], 1);
    }
}

// K2: exclusive scan of 4096-bin histogram
__global__ __launch_bounds__(1024) void scan_kernel(const int* __restrict__ hist,
                                                    int* __restrict__ cellstart) {
    __shared__ int buf[1024];
    int t = threadIdx.x;
    int h0 = hist[4 * t], h1 = hist[4 * t + 1], h2 = hist[4 * t + 2], h3 = hist[4 * t + 3];
    int s = h0 + h1 + h2 + h3;
    buf[t] = s;
    __syncthreads();
    for (int off = 1; off < 1024; off <<= 1) {
        int v = (t >= off) ? buf[t - off] : 0;
        __syncthreads();
        buf[t] += v;
        __syncthreads();
    }
    int ex = buf[t] - s;
    cellstart[4 * t]     = ex;
    cellstart[4 * t + 1] = ex + h0;
    cellstart[4 * t + 2] = ex + h0 + h1;
    cellstart[4 * t + 3] = ex + h0 + h1 + h2;
}

// K3: scatter into Morton order, packed as (x, y, z, orig_idx_bits)
__global__ void scatter_kernel(const float* __restrict__ sx, const float* __restrict__ sy,
                               const float* __restrict__ sz,
                               const int* __restrict__ cell, const int* __restrict__ rank,
                               const int* __restrict__ cellstart, int N,
                               float4* __restrict__ pts) {
    int i = blockIdx.x * blockDim.x + threadIdx.x;
    if (i < N) {
        int pos = cellstart[cell[i]] + rank[i];
        pts[pos] = make_float4(sx[i], sy[i], sz[i], __int_as_float(i));
    }
}

// K3b: sentinel padding
__global__ void pad_kernel(float4* __restrict__ pts, int N, int cap) {
    int i = N + blockIdx.x * blockDim.x + threadIdx.x;
    if (i < cap) pts[i] = make_float4(1e18f, 1e18f, 1e18f, __int_as_float(0x7fffffff));
}

// K3c: per-chunk init — md vs original point 0, chunk sphere, chunk key, winner coords.
__global__ void init_chunk_kernel(const float4* __restrict__ pts,
                                  const float* __restrict__ coord,
                                  float* __restrict__ mdbuf,
                                  float4* __restrict__ spheres,
                                  u64* __restrict__ ckeys,
                                  float4* __restrict__ wxyz_g) {
    int c = blockIdx.x, lane = threadIdx.x;
    int pos = (c << 6) + lane;
    float4 P = pts[pos];
    int orig = __float_as_int(P.w);
    bool real = (orig != 0x7fffffff);
    float c0x = coord[0], c0y = coord[1], c0z = coord[2];
    float d = sq_dist_nofma(P.x, P.y, P.z, c0x, c0y, c0z);
    float m = real ? d : -3e38f;
    mdbuf[pos] = m;
    u64 kself = pack_key(m, orig, c);
    u64 key = kself;
    float mnx = real ? P.x : 1e30f, mxx = real ? P.x : -1e30f;
    float mny = real ? P.y : 1e30f, mxy = real ? P.y : -1e30f;
    float mnz = real ? P.z : 1e30f, mxz = real ? P.z : -1e30f;
    #pragma unroll
    for (int off = 32; off; off >>= 1) {
        u64 k2 = __shfl_xor(key, off, 64);
        if (k2 > key) key = k2;
        mnx = fminf(mnx, __shfl_xor(mnx, off, 64));
        mxx = fmaxf(mxx, __shfl_xor(mxx, off, 64));
        mny = fminf(mny, __shfl_xor(mny, off, 64));
        mxy = fmaxf(mxy, __shfl_xor(mxy, off, 64));
        mnz = fminf(mnz, __shfl_xor(mnz, off, 64));
        mxz = fmaxf(mxz, __shfl_xor(mxz, off, 64));
    }
    if (kself == key) wxyz_g[c] = make_float4(P.x, P.y, P.z, 0.f);  // unique owner lane
    if (lane == 0) {
        float cx = 0.5f * (mnx + mxx), cy = 0.5f * (mny + mxy), cz = 0.5f * (mnz + mxz);
        float ex = (mxx - mnx) * 0.5f, ey = (mxy - mny) * 0.5f, ez = (mxz - mnz) * 0.5f;
        float r = sqrtf(ex * ex + ey * ey + ez * ez) * 1.0001f + 1e-7f;
        spheres[c] = make_float4(cx, cy, cz, r);
        ckeys[c] = key;
    }
}

// K4: chunked FPS, round-21 = round-7 (measured best, 4990us) + three
// issue-count cuts, selection bit-identical:
// (a) WINNER-PERSISTENCE fast path: when the cached winner lane's md drops,
//     test ballot(md > W || (md==W && s15 > s15w)) — empty <=> the winner is
//     still the chunk argmax under (max md, min orig) tie-break; owner then
//     just rewrites k0's md bits (no DPP reduce, no coord readlanes).
// (b) CLEAN-WAVE skip: cache the wave's posted (key, coords) as uniform regs;
//     recompute the wave argmax only if any owner update fired last step.
// (c) thr cached per lane: recomputed only at init and inside owner updates
//     (it depends only on own k0/S), deleting sqrt+muls from the step path.
__global__ __launch_bounds__(FT, 3)
void fps_kernel(const float4* __restrict__ pts,
                const float* __restrict__ coord,
                const float4* __restrict__ spheres_g, const u64* __restrict__ ckeys_g,
                const float4* __restrict__ wxyz_g,
                int nchunk, int n_dst, int* __restrict__ out_idx) {
#pragma clang fp contract(off)
    __shared__ u64    wwin[2][16];          // padded: [12..15] stay 0 forever
    __shared__ float4 wcoord[2][NWAVE];

    const int tid = threadIdx.x, lane = tid & 63, wv = tid / 64;
    const int myc = lane * NWAVE + wv;     // lane r of wave wv owns chunk r*NWAVE+wv

    const float c0x = coord[0], c0y = coord[1], c0z = coord[2];

    // ---- register-resident point state (f32x2 pairs; slot 27 = sentinel) ----
    f32x2 px2[NP], py2[NP], pz2[NP], md2[NP];
    u32   po16[NP];                        // packed 16-bit orig; 0xFFFF = sentinel
    #pragma unroll
    for (int i = 0; i < NP; ++i) {
        px2[i] = (f32x2)(0.f); py2[i] = (f32x2)(0.f);
        pz2[i] = (f32x2)(0.f); md2[i] = (f32x2)(0.f);
        po16[i] = 0xFFFFFFFFu;
    }
    #pragma unroll
    for (int r = 0; r < NSLOT; ++r) {
        int c = r * NWAVE + wv;
        float x = 0.f, y = 0.f, z = 0.f, md = 0.f;
        u32 o = 0xFFFFu;
        if (c < nchunk) {                           // wave-uniform
            float4 P = pts[(c << 6) + lane];
            int orig = __float_as_int(P.w);
            x = P.x; y = P.y; z = P.z;
            if (orig != 0x7fffffff) {
                o = (u32)orig;
                // bit-identical to init_chunk's md -> keys stay consistent
                md = sq_dist_nofma(x, y, z, c0x, c0y, c0z);
            }
        }
        const int i = r >> 1;
        if (r & 1) { px2[i].y = x; py2[i].y = y; pz2[i].y = z; md2[i].y = md;
                     po16[i] = (po16[i] & 0x0000FFFFu) | (o << 16); }
        else       { px2[i].x = x; py2[i].x = y; pz2[i].x = z; md2[i].x = md;
                     po16[i] = (po16[i] & 0xFFFF0000u) | o; }
    }

    // ---- per-owned-chunk state (lane r of wave wv owns chunk r*NWAVE+wv) ----
    u64 k0 = 0ull;                          // own chunk's key (maxmd | orig | chunk)
    float wx = 0.f, wy = 0.f, wz = 0.f;     // own chunk's winner coords
    int wlane = 0;                          // own chunk's winner LANE within its wave
    float4 S = make_float4(1e18f, 1e18f, 1e18f, 0.f);   // own chunk's sphere
    if (lane < NSLOT && myc < nchunk) {
        k0 = ckeys_g[myc];
        float4 W = wxyz_g[myc];
        wx = W.x; wy = W.y; wz = W.z;
        S = spheres_g[myc];
    }
    // cached prune threshold (recomputed only when k0 changes)
    float thr = -1.0f;
    if (k0 != 0ull) {
        float maxmd = __uint_as_float((u32)(k0 >> 24));
        float t0 = sqrtf(maxmd) * 1.0001f + S.w;
        thr = t0 * t0 * 1.0002f + 1e-12f;
    }
    // derive winner lane: match k0's static low-24 bits against reconstructed plo
    #pragma unroll
    for (int r = 0; r < NSLOT; ++r) {
        u32 lov = (u32)__builtin_amdgcn_readlane((int)(u32)k0, r) & 0xFFFFFFu;
        u32 o = (po16[r >> 1] >> (16 * (r & 1))) & 0xFFFFu;
        u32 pl = ((0x7FFFu - o) << 9) | (u32)(r * NWAVE + wv);
        u64 mk = __ballot(o != 0xFFFFu && pl == lov);
        if (lane == r && mk) wlane = __ffsll(mk) - 1;
    }

    // cached wave winner (uniform) + dirty flag
    u64 ck = 0ull; float cwx = 0.f, cwy = 0.f, cwz = 0.f;
    bool wavedirty = true;

    if (tid == 0) out_idx[0] = 0;
    if (tid < 16) { wwin[0][tid] = 0ull; wwin[1][tid] = 0ull; }   // pad zeros
    __syncthreads();

    int par = 1;
    for (int s = 1; s < n_dst; ++s) {
        // A: recompute wave argmax only if something changed last step.
        if (wavedirty) {
            wavedirty = false;
            u32 hi  = (u32)(k0 >> 32);
            u32 mhi = wave_max_u32(hi);
            u64 tbA = __ballot(hi == mhi);
            u32 mlo;
            if (__popcll(tbA) == 1) {
                mlo = (u32)__builtin_amdgcn_readlane((int)(u32)k0,
                                                     (int)(__ffsll((long long)tbA) - 1));
            } else {
                mlo = wave_max_u32(hi == mhi ? (u32)k0 : 0u);
            }
            ck = ((u64)mhi << 32) | mlo;
            u64 tbo = __ballot(k0 == ck && k0 != 0ull);   // unique owner
            int wl0 = (int)(__ffsll((long long)tbo) - 1);
            cwx = readlane_f(wx, wl0);
            cwy = readlane_f(wy, wl0);
            cwz = readlane_f(wz, wl0);
        }
        if (lane == 0) {
            wwin[par][wv]   = ck;
            wcoord[par][wv] = make_float4(cwx, cwy, cwz, 0.f);
        }
        __syncthreads();                    // the ONLY barrier per step

        // cross-wave scan via DPP row16 max (lanes 0-15 mirror across rows)
        u64 wval = wwin[par][lane & 15];
        u32 shi = (u32)(wval >> 32), slo = (u32)wval;
        u32 mhiS = row16_max_u32(shi);
        u64 tbS = __ballot((lane < 16) && shi == mhiS);
        u32 mloS; int wb;
        if (__popcll(tbS) == 1) {
            wb = (int)(__ffsll((long long)tbS) - 1);
            mloS = (u32)__builtin_amdgcn_readlane((int)slo, wb);
        } else {
            mloS = row16_max_u32((shi == mhiS && lane < 16) ? slo : 0u);
            wb = (int)(__ffsll((long long)__ballot((lane < 16) && shi == mhiS
                                                   && slo == mloS)) - 1);
        }
        u64 kb = ((u64)mhiS << 32) | mloS;
        float4 C4 = wcoord[par][wb];
        float ncx = C4.x, ncy = C4.y, ncz = C4.z;
        if (tid == 0) out_idx[s] = (int)(0x7FFFu - (u32)((kb >> 9) & 0x7FFFull));
        par ^= 1;

        // B: prune own chunk (cached thr). Winner's chunk never pruned.
        bool act = false;
        if (k0 != 0ull) {
            float Dx = ncx - S.x, Dy = ncy - S.y, Dz = ncz - S.z;
            float D2 = Dx * Dx + Dy * Dy + Dz * Dz;
            act = (D2 <= thr);
        }
        u64 m = __ballot(act);              // bit r -> chunk r*NWAVE+wv active

        // C: packed pair dist pass over active pairs; per-changed-chunk update
        // with winner-persistence fast path; full reduce only on winner change.
        f32x2 nx2; nx2.x = ncx; nx2.y = ncx;
        f32x2 ny2; ny2.x = ncy; ny2.y = ncy;
        f32x2 nz2; nz2.x = ncz; nz2.y = ncz;
        #pragma unroll
        for (int i = 0; i < NP; ++i) {
            if ((m >> (2 * i)) & 3ull) {    // either slot of the pair active
                f32x2 dx = px2[i] - nx2;
                f32x2 dy = py2[i] - ny2;
                f32x2 dz = pz2[i] - nz2;
                f32x2 dd = (dx * dx + dy * dy) + dz * dz;   // contract(off)
                bool ca = dd.x < md2[i].x;  // pruned/sentinel slots: never true
                bool cb = dd.y < md2[i].y;
                u64 mca = __ballot(ca);
                u64 mcb = __ballot(cb);
                md2[i].x = ca ? dd.x : md2[i].x;
                md2[i].y = cb ? dd.y : md2[i].y;
                #pragma unroll
                for (int h = 0; h < 2; ++h) {
                    const int r = 2 * i + h;
                    u64 mchg = h ? mcb : mca;
                    if (mchg) {
                        int wlo = __builtin_amdgcn_readlane(wlane, r);
                        if ((mchg >> wlo) & 1ull) {
                            wavedirty = true;
                            float mdv = h ? md2[i].y : md2[i].x;
                            u32 s15v = (po16[i] >> (16 * h)) & 0xFFFFu;
                            s15v = (0x7FFFu - s15v) & 0xFFFFu;   // sentinel 0xFFFF -> 0x8000? no:
                            // NOTE: sentinel orig=0xFFFF gives s15v=(0x7FFF-0xFFFF)&0xFFFF
                            // = 0x8000 which would corrupt the compare; recompute properly:
                            u32 ov = (po16[i] >> (16 * h)) & 0xFFFFu;
                            s15v = (ov == 0xFFFFu) ? 0u : (0x7FFFu - ov);
                            u32 Wb   = (u32)__builtin_amdgcn_readlane(
                                           __float_as_int(mdv), wlo);
                            u32 ow   = ((u32)__builtin_amdgcn_readlane(
                                           (int)po16[i], wlo) >> (16 * h)) & 0xFFFFu;
                            u32 s15w = 0x7FFFu - ow;             // winner is real
                            float Wf = __uint_as_float(Wb);
                            bool worse = (mdv > Wf) ||
                                         (__float_as_uint(mdv) == Wb && s15v > s15w);
                            if (!__ballot(worse)) {
                                // fast path: winner persists with smaller md
                                if (lane == r) {
                                    k0 = ((u64)Wb << 24) | (u32)(k0 & 0xFFFFFFull);
                                    float t0 = sqrtf(Wf) * 1.0001f + S.w;
                                    thr = t0 * t0 * 1.0002f + 1e-12f;
                                }
                            } else {
                                // full reduce (R7 path, bit-identical)
                                float pm = mdv;
                                u32 v  = __float_as_uint(pm);   // sentinels contribute 0
                                u32 mv = wave_max_u32(v);
                                u64 tb = __ballot(v == mv);
                                int wl; u32 low;
                                if (__popcll(tb) == 1) {        // unique winner (common)
                                    wl = (int)(__ffsll((long long)tb) - 1);
                                    u32 pw = (u32)__builtin_amdgcn_readlane((int)po16[i], wl);
                                    u32 o2 = (pw >> (16 * h)) & 0xFFFFu;
                                    low = ((0x7FFFu - o2) << 9) | (u32)(r * NWAVE + wv);
                                } else {                        // exact md bit-tie (rare)
                                    u32 o2 = (po16[i] >> (16 * h)) & 0xFFFFu;
                                    u32 pl = (v == mv && o2 != 0xFFFFu)
                                           ? (((0x7FFFu - o2) << 9) | (u32)(r * NWAVE + wv)) : 0u;
                                    u32 t2 = wave_max_u32(pl);
                                    wl = (int)(__ffsll((long long)__ballot(pl == t2 && pl != 0u)) - 1);
                                    low = t2;
                                }
                                float sxr = h ? px2[i].y : px2[i].x;
                                float syr = h ? py2[i].y : py2[i].x;
                                float szr = h ? pz2[i].y : pz2[i].x;
                                float bx = readlane_f(sxr, wl);
                                float by = readlane_f(syr, wl);
                                float bz = readlane_f(szr, wl);
                                if (lane == r) {    // deliver to owner lane (same wave)
                                    k0 = ((u64)mv << 24) | low;
                                    wx = bx; wy = by; wz = bz; wlane = wl;
                                    float maxmd = __uint_as_float(mv);
                                    float t0 = sqrtf(maxmd) * 1.0001f + S.w;
                                    thr = t0 * t0 * 1.0002f + 1e-12f;
                                }
                            }
                        }
                    }
                }
            }
        }
    }
}

// K5: ball query, one wave per dst. First K in-radius src indices in ascending order.
__global__ void ball_kernel(const float* __restrict__ sx, const float* __restrict__ sy,
                            const float* __restrict__ sz, const float* __restrict__ sn,
                            const int* __restrict__ idx,
                            const float* __restrict__ coord, const int* __restrict__ batch,
                            int N, int n_dst,
                            float* __restrict__ out_coord, float* __restrict__ out_esrc,
                            float* __restrict__ out_edst, float* __restrict__ out_deg,
                            float* __restrict__ out_batch,
                            int* __restrict__ nbr_i, int* __restrict__ deg_i) {
    const int d    = blockIdx.x;
    const int lane = threadIdx.x;   // block of 64
    __shared__ int nbr[KNBR];

    const int id = idx[d];
    const float cx = sx[id], cy = sy[id], cz = sz[id];
    const float dn = sn[id];
    const float RR = (float)(0.08 * 0.08);

    int cnt = 0;
    for (int base = 0; base < N && cnt < KNBR; base += 64) {
        int i = base + lane;
        bool in = false;
        if (i < N) {
            float t     = __fmul_rn(sx[i], cx);
            float inner = __fmaf_rn(sy[i], cy, t);
            inner       = __fmaf_rn(sz[i], cz, inner);
            float d2    = __fsub_rn(__fadd_rn(dn, sn[i]), __fmul_rn(2.0f, inner));
            in = (d2 <= RR);
        }
        unsigned long long m = __ballot(in);
        int pos = cnt + __popcll(m & ((1ull << lane) - 1ull));
        if (in && pos < KNBR) nbr[pos] = i;
        cnt += (int)__popcll(m);
    }
    __syncthreads();

    int deg = cnt < KNBR ? cnt : KNBR;
    if (lane < KNBR) {
        int e = (lane < deg) ? nbr[lane] : -1;
        out_esrc[d * KNBR + lane] = (float)e;
        out_edst[d * KNBR + lane] = (float)((lane < deg) ? d : -1);
        nbr_i[d * KNBR + lane] = e;
    }
    if (lane == 0) { out_deg[d] = (float)deg; deg_i[d] = deg; }
    if (lane < 3)  out_coord[d * 3 + lane] = coord[id * 3 + lane];
    if (lane == 3) out_batch[d] = (float)batch[id];
}

// K6: scatter-mean of gathered features. One block per dst, one thread per feature dim.
__global__ void agg_kernel(const float* __restrict__ feat,
                           const int* __restrict__ nbr_i, const int* __restrict__ deg_i,
                           int F, float* __restrict__ out_feat) {
    const int d = blockIdx.x;
    const int t = threadIdx.x;  // F threads
    const int deg = deg_i[d];
    float acc = 0.0f;
    for (int k = 0; k < deg; ++k) {
        int nb = nbr_i[d * KNBR + k];
        acc = __fadd_rn(acc, feat[nb * F + t]);
    }
    float den = (float)(deg > 0 ? deg : 1);
    out_feat[d * F + t] = acc / den;
}

extern "C" void kernel_launch(void* const* d_in, const int* in_sizes, int n_in,
                              void* d_out, int out_size, void* d_ws, size_t ws_size,
                              hipStream_t stream) {
    const float* coord = (const float*)d_in[0];
    const float* feat  = (const float*)d_in[1];
    const int*   batch = (const int*)d_in[2];

    const int N      = in_sizes[0] / 3;
    const int F      = in_sizes[1] / N;
    const int n_dst  = N / 4;                 // RATIO = 0.25
    const int nchunk = (N + 63) / 64;         // 313

    // workspace layout (pts 16B-aligned: 4N floats precede it; N=20000 -> 320000 B)
    float*  sx      = (float*)d_ws;
    float*  sy      = sx + N;
    float*  sz      = sy + N;
    float*  sn      = sz + N;
    float4* pts     = (float4*)(sn + N);      // FCAP packed points
    float4* spheres = pts + FCAP;             // MAXCHUNK
    float4* wxyz_g  = spheres + MAXCHUNK;     // MAXCHUNK winner coords
    float*  mdbuf   = (float*)(wxyz_g + MAXCHUNK);    // FCAP floats
    u64*    ckeys   = (u64*)(mdbuf + FCAP);   // MAXCHUNK (8B-aligned)
    int*    cell      = (int*)(ckeys + MAXCHUNK);
    int*    rank      = cell + N;
    int*    hist      = rank + N;
    int*    cellstart = hist + NCELL;
    int*    idx       = cellstart + NCELL;
    int*    nbr_i     = idx + n_dst;
    int*    deg_i     = nbr_i + n_dst * KNBR;

    // output layout (all float32), reference return order
    float* out     = (float*)d_out;
    float* o_coord = out;                         // n_dst*3
    float* o_feat  = o_coord + (size_t)n_dst * 3; // n_dst*F
    float* o_esrc  = o_feat  + (size_t)n_dst * F; // n_dst*K
    float* o_edst  = o_esrc  + (size_t)n_dst * KNBR;
    float* o_deg   = o_edst  + (size_t)n_dst * KNBR;
    float* o_batch = o_deg   + n_dst;

    hipMemsetAsync(hist, 0, NCELL * sizeof(int), stream);
    prep_kernel<<<(N + 255) / 256, 256, 0, stream>>>(coord, N, sx, sy, sz, sn,
                                                     cell, rank, hist);
    scan_kernel<<<1, 1024, 0, stream>>>(hist, cellstart);
    scatter_kernel<<<(N + 255) / 256, 256, 0, stream>>>(sx, sy, sz, cell, rank,
                                                        cellstart, N, pts);
    pad_kernel<<<(nchunk * 64 - N + 255) / 256, 256, 0, stream>>>(pts, N, nchunk * 64);
    init_chunk_kernel<<<nchunk, 64, 0, stream>>>(pts, coord, mdbuf, spheres, ckeys,
                                                 wxyz_g);
    fps_kernel<<<1, FT, 0, stream>>>(pts, coord, spheres, ckeys, wxyz_g,
                                     nchunk, n_dst, idx);
    ball_kernel<<<n_dst, 64, 0, stream>>>(sx, sy, sz, sn, idx, coord, batch, N, n_dst,
                                          o_coord, o_esrc, o_edst, o_deg, o_batch,
                                          nbr_i, deg_i);
    agg_kernel<<<n_dst, F, 0, stream>>>(feat, nbr_i, deg_i, F, o_feat);
}

// Round 10
// 5102.391 us; speedup vs baseline: 1.8575x; 1.5141x over previous
//
#include <hip/hip_runtime.h>

#define KNBR 32
#define NCELL 4096        // 16^3 Morton cells
#define MAXCHUNK 320      // ceil(20000/64)=313 <= 320
#define FCAP (MAXCHUNK * 64)
#define FT 1024           // fps threads: 16 waves
#define NWAVE (FT / 64)   // 16
#define NSLOT 20          // chunks per wave: 20*16 = 320 >= 313
#define NP 10             // f32x2 pairs per array (NSLOT even: no pad slot)

typedef unsigned long long u64;
typedef unsigned int u32;
typedef float f32x2 __attribute__((ext_vector_type(2)));

// Reference-matching squared distance: ((dx*dx + dy*dy) + dz*dz), no FMA contraction.
__device__ __forceinline__ float sq_dist_nofma(float px, float py, float pz,
                                               float cx, float cy, float cz) {
    float dx = __fsub_rn(px, cx);
    float dy = __fsub_rn(py, cy);
    float dz = __fsub_rn(pz, cz);
    return __fadd_rn(__fadd_rn(__fmul_rn(dx, dx), __fmul_rn(dy, dy)), __fmul_rn(dz, dz));
}

__device__ __forceinline__ unsigned spread4(unsigned v) {
    return (v & 1u) | ((v & 2u) << 2) | ((v & 4u) << 4) | ((v & 8u) << 6);
}

// key = md_bits<<24 | (0x7FFF-orig)<<9 | chunk  (orig<32768, chunk<512).
// u64 max == (max md, then min orig); chunk id rides along. Sentinels -> key 0.
__device__ __forceinline__ u64 pack_key(float md, int orig, int c) {
    return (orig != 0x7fffffff)
        ? (((u64)__float_as_uint(md) << 24) | ((u64)(0x7FFFu - (u32)orig) << 9) | (u64)c)
        : 0ull;
}

// Canonical CDNA wave64 u32 max-reduction via DPP; lane 63 holds the max;
// readlane broadcasts. Out-of-pattern lanes contribute 0 (identity for unsigned max).
template<int CTRL, int RM>
__device__ __forceinline__ u32 dppmax_step(u32 v) {
    u32 t = (u32)__builtin_amdgcn_update_dpp(0, (int)v, CTRL, RM, 0xf, false);
    return t > v ? t : v;
}
__device__ __forceinline__ u32 wave_max_u32(u32 v) {
    v = dppmax_step<0x111, 0xf>(v);   // row_shr:1
    v = dppmax_step<0x112, 0xf>(v);   // row_shr:2
    v = dppmax_step<0x114, 0xf>(v);   // row_shr:4
    v = dppmax_step<0x118, 0xf>(v);   // row_shr:8
    v = dppmax_step<0x142, 0xa>(v);   // row_bcast:15 -> rows 1,3
    v = dppmax_step<0x143, 0xc>(v);   // row_bcast:31 -> rows 2,3
    return (u32)__builtin_amdgcn_readlane((int)v, 63);
}
// 16-lane row max (lanes 0-15 of each row identical input -> lane 15 has max)
__device__ __forceinline__ u32 row16_max_u32(u32 v) {
    v = dppmax_step<0x111, 0xf>(v);   // row_shr:1
    v = dppmax_step<0x112, 0xf>(v);   // row_shr:2
    v = dppmax_step<0x114, 0xf>(v);   // row_shr:4
    v = dppmax_step<0x118, 0xf>(v);   // row_shr:8
    return (u32)__builtin_amdgcn_readlane((int)v, 15);
}

// K1: AoS -> SoA + norms + Morton cell id + within-cell rank (counting-sort pass 1)
__global__ void prep_kernel(const float* __restrict__ coord, int N,
                            float* __restrict__ sx, float* __restrict__ sy,
                            float* __restrict__ sz, float* __restrict__ sn,
                            int* __restrict__ cell, int* __restrict__ rank,
                            int* __restrict__ hist) {
    int i = blockIdx.x * blockDim.x + threadIdx.x;
    if (i < N) {
        float x = coord[3 * i + 0];
        float y = coord[3 * i + 1];
        float z = coord[3 * i + 2];
        sx[i] = x; sy[i] = y; sz[i] = z;
        sn[i] = __fadd_rn(__fadd_rn(__fmul_rn(x, x), __fmul_rn(y, y)), __fmul_rn(z, z));
        int ix = (int)(x * 16.0f); ix = ix < 0 ? 0 : (ix > 15 ? 15 : ix);
        int iy = (int)(y * 16.0f); iy = iy < 0 ? 0 : (iy > 15 ? 15 : iy);
        int iz = (int)(z * 16.0f); iz = iz < 0 ? 0 : (iz > 15 ? 15 : iz);
        unsigned mc = spread4(ix) | (spread4(iy) << 1) | (spread4(iz) << 2);
        cell[i] = (int)mc;
        rank[i] = atomicAdd(&hist[mc], 1);
    }
}

// K2: exclusive scan of 4096-bin histogram
__global__ __launch_bounds__(1024) void scan_kernel(const int* __restrict__ hist,
                                                    int* __restrict__ cellstart) {
    __shared__ int buf[1024];
    int t = threadIdx.x;
    int h0 = hist[4 * t], h1 = hist[4 * t + 1], h2 = hist[4 * t + 2], h3 = hist[4 * t + 3];
    int s = h0 + h1 + h2 + h3;
    buf[t] = s;
    __syncthreads();
    for (int off = 1; off < 1024; off <<= 1) {
        int v = (t >= off) ? buf[t - off] : 0;
        __syncthreads();
        buf[t] += v;
        __syncthreads();
    }
    int ex = buf[t] - s;
    cellstart[4 * t]     = ex;
    cellstart[4 * t + 1] = ex + h0;
    cellstart[4 * t + 2] = ex + h0 + h1;
    cellstart[4 * t + 3] = ex + h0 + h1 + h2;
}

// K3: scatter into Morton order, packed as (x, y, z, orig_idx_bits)
__global__ void scatter_kernel(const float* __restrict__ sx, const float* __restrict__ sy,
                               const float* __restrict__ sz,
                               const int* __restrict__ cell, const int* __restrict__ rank,
                               const int* __restrict__ cellstart, int N,
                               float4* __restrict__ pts) {
    int i = blockIdx.x * blockDim.x + threadIdx.x;
    if (i < N) {
        int pos = cellstart[cell[i]] + rank[i];
        pts[pos] = make_float4(sx[i], sy[i], sz[i], __int_as_float(i));
    }
}

// K3b: sentinel padding
__global__ void pad_kernel(float4* __restrict__ pts, int N, int cap) {
    int i = N + blockIdx.x * blockDim.x + threadIdx.x;
    if (i < cap) pts[i] = make_float4(1e18f, 1e18f, 1e18f, __int_as_float(0x7fffffff));
}

// K3c: per-chunk init — md vs original point 0, chunk sphere, chunk key, winner coords.
__global__ void init_chunk_kernel(const float4* __restrict__ pts,
                                  const float* __restrict__ coord,
                                  float* __restrict__ mdbuf,
                                  float4* __restrict__ spheres,
                                  u64* __restrict__ ckeys,
                                  float4* __restrict__ wxyz_g) {
    int c = blockIdx.x, lane = threadIdx.x;
    int pos = (c << 6) + lane;
    float4 P = pts[pos];
    int orig = __float_as_int(P.w);
    bool real = (orig != 0x7fffffff);
    float c0x = coord[0], c0y = coord[1], c0z = coord[2];
    float d = sq_dist_nofma(P.x, P.y, P.z, c0x, c0y, c0z);
    float m = real ? d : -3e38f;
    mdbuf[pos] = m;
    u64 kself = pack_key(m, orig, c);
    u64 key = kself;
    float mnx = real ? P.x : 1e30f, mxx = real ? P.x : -1e30f;
    float mny = real ? P.y : 1e30f, mxy = real ? P.y : -1e30f;
    float mnz = real ? P.z : 1e30f, mxz = real ? P.z : -1e30f;
    #pragma unroll
    for (int off = 32; off; off >>= 1) {
        u64 k2 = __shfl_xor(key, off, 64);
        if (k2 > key) key = k2;
        mnx = fminf(mnx, __shfl_xor(mnx, off, 64));
        mxx = fmaxf(mxx, __shfl_xor(mxx, off, 64));
        mny = fminf(mny, __shfl_xor(mny, off, 64));
        mxy = fmaxf(mxy, __shfl_xor(mxy, off, 64));
        mnz = fminf(mnz, __shfl_xor(mnz, off, 64));
        mxz = fmaxf(mxz, __shfl_xor(mxz, off, 64));
    }
    if (kself == key) wxyz_g[c] = make_float4(P.x, P.y, P.z, 0.f);  // unique owner lane
    if (lane == 0) {
        float cx = 0.5f * (mnx + mxx), cy = 0.5f * (mny + mxy), cz = 0.5f * (mnz + mxz);
        float ex = (mxx - mnx) * 0.5f, ey = (mxy - mny) * 0.5f, ez = (mxz - mnz) * 0.5f;
        float r = sqrtf(ex * ex + ey * ey + ez * ez) * 1.0001f + 1e-7f;
        spheres[c] = make_float4(cx, cy, cz, r);
        ckeys[c] = key;
    }
}

// K4: chunked FPS, round-22 = round-7 structure VERBATIM (measured best,
// 4990us) with only the parallelism parameters changed: 16 waves x 20 slots
// (was 12 x 27). Validated lever (R1->R2: 8->12 waves = -21%): fewer
// serialized per-chunk reduces per wave on early steps (<=20 vs <=27), active
// set spread over more waves mid-run, row16 scan now fits exactly (16 wwin
// entries). Selection sequence bit-identical to R7/R2.
__global__ __launch_bounds__(FT, 4)
void fps_kernel(const float4* __restrict__ pts,
                const float* __restrict__ coord,
                const float4* __restrict__ spheres_g, const u64* __restrict__ ckeys_g,
                const float4* __restrict__ wxyz_g,
                int nchunk, int n_dst, int* __restrict__ out_idx) {
#pragma clang fp contract(off)
    __shared__ u64    wwin[2][16];
    __shared__ float4 wcoord[2][NWAVE];

    const int tid = threadIdx.x, lane = tid & 63, wv = tid / 64;
    const int myc = lane * NWAVE + wv;     // lane r of wave wv owns chunk r*NWAVE+wv

    const float c0x = coord[0], c0y = coord[1], c0z = coord[2];

    // ---- register-resident point state (f32x2 pairs) ----
    f32x2 px2[NP], py2[NP], pz2[NP], md2[NP];
    u32   po16[NP];                        // packed 16-bit orig; 0xFFFF = sentinel
    #pragma unroll
    for (int r = 0; r < NSLOT; ++r) {
        int c = r * NWAVE + wv;
        float x = 0.f, y = 0.f, z = 0.f, md = 0.f;
        u32 o = 0xFFFFu;
        if (c < nchunk) {                           // wave-uniform
            float4 P = pts[(c << 6) + lane];
            int orig = __float_as_int(P.w);
            x = P.x; y = P.y; z = P.z;
            if (orig != 0x7fffffff) {
                o = (u32)orig;
                // bit-identical to init_chunk's md -> keys stay consistent
                md = sq_dist_nofma(x, y, z, c0x, c0y, c0z);
            }
        }
        const int i = r >> 1;
        if (r & 1) { px2[i].y = x; py2[i].y = y; pz2[i].y = z; md2[i].y = md;
                     po16[i] = (po16[i] & 0x0000FFFFu) | (o << 16); }
        else       { px2[i].x = x; py2[i].x = y; pz2[i].x = z; md2[i].x = md;
                     po16[i] = o; }
    }

    // ---- per-owned-chunk state (lane r of wave wv owns chunk r*NWAVE+wv) ----
    u64 k0 = 0ull;                          // own chunk's key (maxmd | orig | chunk)
    float wx = 0.f, wy = 0.f, wz = 0.f;     // own chunk's winner coords
    int wlane = 0;                          // own chunk's winner LANE within its wave
    float4 S = make_float4(1e18f, 1e18f, 1e18f, 0.f);   // own chunk's sphere
    if (lane < NSLOT && myc < nchunk) {
        k0 = ckeys_g[myc];
        float4 W = wxyz_g[myc];
        wx = W.x; wy = W.y; wz = W.z;
        S = spheres_g[myc];
    }
    // derive winner lane: match k0's static low-24 bits against reconstructed plo
    #pragma unroll
    for (int r = 0; r < NSLOT; ++r) {
        u32 lov = (u32)__builtin_amdgcn_readlane((int)(u32)k0, r) & 0xFFFFFFu;
        u32 o = (po16[r >> 1] >> (16 * (r & 1))) & 0xFFFFu;
        u32 pl = ((0x7FFFu - o) << 9) | (u32)(r * NWAVE + wv);
        u64 mk = __ballot(o != 0xFFFFu && pl == lov);
        if (lane == r && mk) wlane = __ffsll(mk) - 1;
    }

    if (tid == 0) out_idx[0] = 0;
    if (tid < 16) { wwin[0][tid] = 0ull; wwin[1][tid] = 0ull; }
    __syncthreads();

    int par = 1;
    for (int s = 1; s < n_dst; ++s) {
        // A: wave argmax over k0. One DPP chain on the hi word; unique-winner
        // shortcut grabs the lo word with a single readlane (tie ~0.3% of steps).
        u32 hi  = (u32)(k0 >> 32);
        u32 mhi = wave_max_u32(hi);
        u64 tbA = __ballot(hi == mhi);
        u32 mlo;
        if (__popcll(tbA) == 1) {
            mlo = (u32)__builtin_amdgcn_readlane((int)(u32)k0,
                                                 (int)(__ffsll((long long)tbA) - 1));
        } else {
            mlo = wave_max_u32(hi == mhi ? (u32)k0 : 0u);
        }
        u64 k = ((u64)mhi << 32) | mlo;
        if (k0 == k && k0 != 0ull) {        // unique owner (keys embed chunk id)
            wwin[par][wv]   = k;
            wcoord[par][wv] = make_float4(wx, wy, wz, 0.f);
        }
        // prune threshold: depends only on own k0/S -> hoisted off the
        // post-barrier critical path
        float thr = -1.0f;
        if (k0 != 0ull) {
            float maxmd = __uint_as_float((u32)(k0 >> 24));
            float t0 = sqrtf(maxmd) * 1.0001f + S.w;
            thr = t0 * t0 * 1.0002f + 1e-12f;
        }
        __syncthreads();                    // the ONLY barrier per step

        // cross-wave scan via DPP row16 max (lanes 0-15 mirror across rows)
        u64 wval = wwin[par][lane & 15];
        u32 shi = (u32)(wval >> 32), slo = (u32)wval;
        u32 mhiS = row16_max_u32(shi);
        u64 tbS = __ballot((lane < 16) && shi == mhiS);
        u32 mloS; int wb;
        if (__popcll(tbS) == 1) {
            wb = (int)(__ffsll((long long)tbS) - 1);
            mloS = (u32)__builtin_amdgcn_readlane((int)slo, wb);
        } else {
            mloS = row16_max_u32((shi == mhiS && lane < 16) ? slo : 0u);
            wb = (int)(__ffsll((long long)__ballot((lane < 16) && shi == mhiS
                                                   && slo == mloS)) - 1);
        }
        u64 kb = ((u64)mhiS << 32) | mloS;
        float4 C4 = wcoord[par][wb];
        float ncx = C4.x, ncy = C4.y, ncz = C4.z;
        if (tid == 0) out_idx[s] = (int)(0x7FFFu - (u32)((kb >> 9) & 0x7FFFull));
        par ^= 1;

        // B: prune own chunk (registers only). Winner's chunk never pruned.
        bool act = false;
        if (k0 != 0ull) {
            float Dx = ncx - S.x, Dy = ncy - S.y, Dz = ncz - S.z;
            float D2 = Dx * Dx + Dy * Dy + Dz * Dz;
            act = (D2 <= thr);
        }
        u64 m = __ballot(act);              // bit r -> chunk r*NWAVE+wv active

        // C: packed pair dist pass over active pairs; eager per-slot reduces
        // with winner-lane filter (bit-identical semantics to round 2).
        f32x2 nx2; nx2.x = ncx; nx2.y = ncx;
        f32x2 ny2; ny2.x = ncy; ny2.y = ncy;
        f32x2 nz2; nz2.x = ncz; nz2.y = ncz;
        #pragma unroll
        for (int i = 0; i < NP; ++i) {
            if ((m >> (2 * i)) & 3ull) {    // either slot of the pair active
                f32x2 dx = px2[i] - nx2;
                f32x2 dy = py2[i] - ny2;
                f32x2 dz = pz2[i] - nz2;
                f32x2 dd = (dx * dx + dy * dy) + dz * dz;   // contract(off)
                bool ca = dd.x < md2[i].x;  // pruned/sentinel slots: never true
                bool cb = dd.y < md2[i].y;
                u64 mca = __ballot(ca);
                u64 mcb = __ballot(cb);
                md2[i].x = ca ? dd.x : md2[i].x;
                md2[i].y = cb ? dd.y : md2[i].y;
                #pragma unroll
                for (int h = 0; h < 2; ++h) {
                    const int r = 2 * i + h;
                    u64 mchg = h ? mcb : mca;
                    if (mchg) {
                        int wlo = __builtin_amdgcn_readlane(wlane, r);
                        if ((mchg >> wlo) & 1ull) {
                            float pm = h ? md2[i].y : md2[i].x;
                            u32 v  = __float_as_uint(pm);   // sentinels contribute 0
                            u32 mv = wave_max_u32(v);
                            u64 tb = __ballot(v == mv);
                            int wl; u32 low;
                            if (__popcll(tb) == 1) {        // unique winner (common)
                                wl = (int)(__ffsll((long long)tb) - 1);
                                u32 pw = (u32)__builtin_amdgcn_readlane((int)po16[i], wl);
                                u32 ow = (pw >> (16 * h)) & 0xFFFFu;
                                low = ((0x7FFFu - ow) << 9) | (u32)(r * NWAVE + wv);
                            } else {                        // exact md bit-tie (rare)
                                u32 o2 = (po16[i] >> (16 * h)) & 0xFFFFu;
                                u32 pl = (v == mv && o2 != 0xFFFFu)
                                       ? (((0x7FFFu - o2) << 9) | (u32)(r * NWAVE + wv)) : 0u;
                                u32 t2 = wave_max_u32(pl);
                                wl = (int)(__ffsll((long long)__ballot(pl == t2 && pl != 0u)) - 1);
                                low = t2;
                            }
                            float sxr = h ? px2[i].y : px2[i].x;
                            float syr = h ? py2[i].y : py2[i].x;
                            float szr = h ? pz2[i].y : pz2[i].x;
                            float bx = __uint_as_float((u32)__builtin_amdgcn_readlane(__float_as_int(sxr), wl));
                            float by = __uint_as_float((u32)__builtin_amdgcn_readlane(__float_as_int(syr), wl));
                            float bz = __uint_as_float((u32)__builtin_amdgcn_readlane(__float_as_int(szr), wl));
                            if (lane == r) {    // deliver to owner lane (same wave)
                                k0 = ((u64)mv << 24) | low;
                                wx = bx; wy = by; wz = bz; wlane = wl;
                            }
                        }
                    }
                }
            }
        }
    }
}

// K5: ball query, one wave per dst. First K in-radius src indices in ascending order.
__global__ void ball_kernel(const float* __restrict__ sx, const float* __restrict__ sy,
                            const float* __restrict__ sz, const float* __restrict__ sn,
                            const int* __restrict__ idx,
                            const float* __restrict__ coord, const int* __restrict__ batch,
                            int N, int n_dst,
                            float* __restrict__ out_coord, float* __restrict__ out_esrc,
                            float* __restrict__ out_edst, float* __restrict__ out_deg,
                            float* __restrict__ out_batch,
                            int* __restrict__ nbr_i, int* __restrict__ deg_i) {
    const int d    = blockIdx.x;
    const int lane = threadIdx.x;   // block of 64
    __shared__ int nbr[KNBR];

    const int id = idx[d];
    const float cx = sx[id], cy = sy[id], cz = sz[id];
    const float dn = sn[id];
    const float RR = (float)(0.08 * 0.08);

    int cnt = 0;
    for (int base = 0; base < N && cnt < KNBR; base += 64) {
        int i = base + lane;
        bool in = false;
        if (i < N) {
            float t     = __fmul_rn(sx[i], cx);
            float inner = __fmaf_rn(sy[i], cy, t);
            inner       = __fmaf_rn(sz[i], cz, inner);
            float d2    = __fsub_rn(__fadd_rn(dn, sn[i]), __fmul_rn(2.0f, inner));
            in = (d2 <= RR);
        }
        unsigned long long m = __ballot(in);
        int pos = cnt + __popcll(m & ((1ull << lane) - 1ull));
        if (in && pos < KNBR) nbr[pos] = i;
        cnt += (int)__popcll(m);
    }
    __syncthreads();

    int deg = cnt < KNBR ? cnt : KNBR;
    if (lane < KNBR) {
        int e = (lane < deg) ? nbr[lane] : -1;
        out_esrc[d * KNBR + lane] = (float)e;
        out_edst[d * KNBR + lane] = (float)((lane < deg) ? d : -1);
        nbr_i[d * KNBR + lane] = e;
    }
    if (lane == 0) { out_deg[d] = (float)deg; deg_i[d] = deg; }
    if (lane < 3)  out_coord[d * 3 + lane] = coord[id * 3 + lane];
    if (lane == 3) out_batch[d] = (float)batch[id];
}

// K6: scatter-mean of gathered features. One block per dst, one thread per feature dim.
__global__ void agg_kernel(const float* __restrict__ feat,
                           const int* __restrict__ nbr_i, const int* __restrict__ deg_i,
                           int F, float* __restrict__ out_feat) {
    const int d = blockIdx.x;
    const int t = threadIdx.x;  // F threads
    const int deg = deg_i[d];
    float acc = 0.0f;
    for (int k = 0; k < deg; ++k) {
        int nb = nbr_i[d * KNBR + k];
        acc = __fadd_rn(acc, feat[nb * F + t]);
    }
    float den = (float)(deg > 0 ? deg : 1);
    out_feat[d * F + t] = acc / den;
}

extern "C" void kernel_launch(void* const* d_in, const int* in_sizes, int n_in,
                              void* d_out, int out_size, void* d_ws, size_t ws_size,
                              hipStream_t stream) {
    const float* coord = (const float*)d_in[0];
    const float* feat  = (const float*)d_in[1];
    const int*   batch = (const int*)d_in[2];

    const int N      = in_sizes[0] / 3;
    const int F      = in_sizes[1] / N;
    const int n_dst  = N / 4;                 // RATIO = 0.25
    const int nchunk = (N + 63) / 64;         // 313

    // workspace layout (pts 16B-aligned: 4N floats precede it; N=20000 -> 320000 B)
    float*  sx      = (float*)d_ws;
    float*  sy      = sx + N;
    float*  sz      = sy + N;
    float*  sn      = sz + N;
    float4* pts     = (float4*)(sn + N);      // FCAP packed points
    float4* spheres = pts + FCAP;             // MAXCHUNK
    float4* wxyz_g  = spheres + MAXCHUNK;     // MAXCHUNK winner coords
    float*  mdbuf   = (float*)(wxyz_g + MAXCHUNK);    // FCAP floats
    u64*    ckeys   = (u64*)(mdbuf + FCAP);   // MAXCHUNK (8B-aligned)
    int*    cell      = (int*)(ckeys + MAXCHUNK);
    int*    rank      = cell + N;
    int*    hist      = rank + N;
    int*    cellstart = hist + NCELL;
    int*    idx       = cellstart + NCELL;
    int*    nbr_i     = idx + n_dst;
    int*    deg_i     = nbr_i + n_dst * KNBR;

    // output layout (all float32), reference return order
    float* out     = (float*)d_out;
    float* o_coord = out;                         // n_dst*3
    float* o_feat  = o_coord + (size_t)n_dst * 3; // n_dst*F
    float* o_esrc  = o_feat  + (size_t)n_dst * F; // n_dst*K
    float* o_edst  = o_esrc  + (size_t)n_dst * KNBR;
    float* o_deg   = o_edst  + (size_t)n_dst * KNBR;
    float* o_batch = o_deg   + n_dst;

    hipMemsetAsync(hist, 0, NCELL * sizeof(int), stream);
    prep_kernel<<<(N + 255) / 256, 256, 0, stream>>>(coord, N, sx, sy, sz, sn,
                                                     cell, rank, hist);
    scan_kernel<<<1, 1024, 0, stream>>>(hist, cellstart);
    scatter_kernel<<<(N + 255) / 256, 256, 0, stream>>>(sx, sy, sz, cell, rank,
                                                        cellstart, N, pts);
    pad_kernel<<<(nchunk * 64 - N + 255) / 256, 256, 0, stream>>>(pts, N, nchunk * 64);
    init_chunk_kernel<<<nchunk, 64, 0, stream>>>(pts, coord, mdbuf, spheres, ckeys,
                                                 wxyz_g);
    fps_kernel<<<1, FT, 0, stream>>>(pts, coord, spheres, ckeys, wxyz_g,
                                     nchunk, n_dst, idx);
    ball_kernel<<<n_dst, 64, 0, stream>>>(sx, sy, sz, sn, idx, coord, batch, N, n_dst,
                                          o_coord, o_esrc, o_edst, o_deg, o_batch,
                                          nbr_i, deg_i);
    agg_kernel<<<n_dst, F, 0, stream>>>(feat, nbr_i, deg_i, F, o_feat);
}